// Round 4
// baseline (254.334 us; speedup 1.0000x reference)
//
#include <hip/hip_runtime.h>

// Problem dims
#define TT 32
#define BB 8
#define DD 512
#define HH 512
#define RR 32
#define OO 512
#define H2 1024

typedef unsigned long long ull;

// d_ws float-index offsets (~1.66 MB used)
#define OFF_WX    0        // [TT*BB][H2]   262144  (pre-LN then LN'd in place)
#define OFF_HS    262144   // [TT*BB][HH]   131072
#define OFF_COLV  393216   // 16384 ull = 32768 floats: [2][BB][512][2] tagged words

#define AGENT __HIP_MEMORY_SCOPE_AGENT
#define RLX   __ATOMIC_RELAXED

__device__ __forceinline__ ull ld8(const ull* p) {
  return __hip_atomic_load(const_cast<ull*>(p), RLX, AGENT);
}
__device__ __forceinline__ void st8(ull* p, ull v) {
  __hip_atomic_store(p, v, RLX, AGENT);
}
__device__ __forceinline__ float d4(const float4& a, const float4& b) {
  return a.x*b.x + a.y*b.y + a.z*b.z + a.w*b.w;
}

#define HMW_P 528   // 528 % 32 == 16 -> (r*528 + kk) spans banks exactly 2-way (free)

// ---------------- persistent recurrent kernel: 0 barriers, tagged-word sync ----------------
__global__ __launch_bounds__(512, 1) void sgru_persistent(
    const float* __restrict__ h0,     const float* __restrict__ v0,
    const float* __restrict__ dU0,    const float* __restrict__ tE0,
    const float* __restrict__ te0,
    const float* __restrict__ h2h_w,  const float* __restrict__ h2h_b,
    const float* __restrict__ lnh_g,  const float* __restrict__ lnh_b,
    const float* __restrict__ h2mod_w,const float* __restrict__ h2mod_b,
    const float* __restrict__ mod2h_w,const float* __restrict__ mod2h_b,
    const float* __restrict__ alpha_p,const float* __restrict__ tau_p,
    float* __restrict__ ws)
{
  const int tid = threadIdx.x;
  const int b   = blockIdx.x & 7;    // consecutive blockIdx -> XCD round-robin
  const int ir  = blockIdx.x >> 3;   // row-group 0..31
  const int i0  = ir << 4;
  const int il  = tid >> 5;
  const int m   = tid & 31;
  const int gi  = i0 + il;

  const float* Wx = ws + OFF_WX;
  float* hsbuf    = ws + OFF_HS;
  ull* colvT      = (ull*)(ws + OFF_COLV);   // [par][b][gi][2] tagged words

  __shared__ float nh_s[2][HH];       // nh double buffer by parity
  __shared__ float te_s[2][HH];       // te double buffer by parity
  __shared__ float hmw_s[RR * HMW_P]; // staged h2mod_w, pitch 528
  __shared__ float mp_s[RR];
  __shared__ float red_s[2][8];

  const float a_sp  = log1pf(__expf(alpha_p[0]));
  const float inv_a = 1.0f / (a_sp + 1e-8f);
  const float tau   = 1.0f / (1.0f + __expf(-tau_p[0]));
  const float c1t   = 1.0f - tau;

  // ---- register-resident state: dU, tE, w_dv row, w_low row, clip bounds ----
  float4 dUr[4], tEr[4], Wdvr[4], wlo[4], upr[4], lor[4];
  {
    const size_t rowoff = ((size_t)b * HH + gi) * HH;
    const size_t whioff = (size_t)(HH + gi) * HH;
    const size_t wlooff = (size_t)gi * HH;
#pragma unroll
    for (int q = 0; q < 4; ++q) {
      const int J = m + 32*q;
      dUr[q] = *reinterpret_cast<const float4*>(dU0 + rowoff + 4*J);
      tEr[q] = *reinterpret_cast<const float4*>(tE0 + rowoff + 4*J);
      wlo[q] = *reinterpret_cast<const float4*>(h2h_w + wlooff + 4*J);
      const float4 w = *reinterpret_cast<const float4*>(h2h_w + whioff + 4*J);
      Wdvr[q] = w;
      float4 u, l;
      u.x =  fmaxf(1.0f - w.x, 0.0f) * inv_a;  l.x = -fmaxf(1.0f + w.x, 0.0f) * inv_a;
      u.y =  fmaxf(1.0f - w.y, 0.0f) * inv_a;  l.y = -fmaxf(1.0f + w.y, 0.0f) * inv_a;
      u.z =  fmaxf(1.0f - w.z, 0.0f) * inv_a;  l.z = -fmaxf(1.0f + w.z, 0.0f) * inv_a;
      u.w =  fmaxf(1.0f - w.w, 0.0f) * inv_a;  l.w = -fmaxf(1.0f + w.w, 0.0f) * inv_a;
      upr[q] = u; lor[q] = l;
    }
  }

  // ---- per-thread constants in registers ----
  const float rgz = lnh_g[tid],      rbz = lnh_b[tid];
  const float rgd = lnh_g[HH + tid], rbd = lnh_b[HH + tid];
  const float hbl = h2h_b[gi], hbh = h2h_b[HH + gi];
  const float hmb = h2mod_b[tid >> 4];
  const float mw0 = mod2h_w[tid & 31];             // for redundant per-wave rsm
  const float mw1 = mod2h_w[RR + (tid & 31)];
  const float mw2 = mod2h_w[2*RR + (tid & 31)];
  const float mb0 = mod2h_b[0], mb1 = mod2h_b[1], mb2 = mod2h_b[2];
  float vreg = v0[b*HH + tid];

  // ---- prologue: stage LDS ----
  nh_s[1][tid] = h0[b*HH + tid];     // "prev" for t=0
  te_s[0][tid] = te0[b*HH + tid];    // te entering step 0
  for (int idx = tid; idx < RR*HH; idx += 512)
    hmw_s[(idx >> 9)*HMW_P + (idx & 511)] = h2mod_w[idx];
  __syncthreads();

  // ---- prologue post: Wh(0) from h0/dU0, tag=1, parity 0 ----
  {
    const float4* h4p = reinterpret_cast<const float4*>(nh_s[1]);
    float glo = 0.0f, gdv = 0.0f, plast = 0.0f;
#pragma unroll
    for (int q = 0; q < 4; ++q) {
      const float4 h4 = h4p[m + 32*q];
      glo   += d4(wlo[q],  h4);
      gdv   += d4(Wdvr[q], h4);
      plast += d4(dUr[q],  h4);
    }
#pragma unroll
    for (int off = 16; off >= 1; off >>= 1) {
      glo   += __shfl_xor(glo, off);
      gdv   += __shfl_xor(gdv, off);
      plast += __shfl_xor(plast, off);
    }
    if (m == 0) {
      ull* ps = colvT + ((size_t)(0*BB + b)*512 + gi)*2;
      const ull tg = 1ull << 32;
      st8(ps,     tg | (ull)__float_as_uint(glo + hbl));
      st8(ps + 1, tg | (ull)__float_as_uint(gdv + hbh + a_sp*plast));
    }
  }

  float wxz = Wx[(size_t)(0*BB + b)*H2 + tid];
  float wxd = Wx[(size_t)(0*BB + b)*H2 + HH + tid];

  for (int t = 0; t < TT; ++t) {
    const int cur = t & 1;

    // ---- spin-gather: thread tid needs cols (tid, HH+tid), tag t+1 ----
    const ull* slot = colvT + (size_t)(cur*BB + b)*1024;
    ull vz, vd;
    const ull want = (ull)(t + 1);
    for (;;) { vz = ld8(slot + tid*2);     if ((vz >> 32) == want) break; __builtin_amdgcn_s_sleep(1); }
    for (;;) { vd = ld8(slot + tid*2 + 1); if ((vd >> 32) == want) break; __builtin_amdgcn_s_sleep(1); }
    const float whz = __uint_as_float((unsigned)vz);
    const float whd = __uint_as_float((unsigned)vd);

    // ---- LN stats over 1024 (block-redundant, bitwise identical) ----
    float s1 = whz + whd, s2 = whz*whz + whd*whd;
#pragma unroll
    for (int off = 32; off >= 1; off >>= 1) {
      s1 += __shfl_xor(s1, off);
      s2 += __shfl_xor(s2, off);
    }
    if ((tid & 63) == 0) { red_s[0][tid >> 6] = s1; red_s[1][tid >> 6] = s2; }
    __syncthreads();   // also protects nh_s/te_s writes below vs prior-step readers
    s1 = 0.0f; s2 = 0.0f;
#pragma unroll
    for (int w = 0; w < 8; ++w) { s1 += red_s[0][w]; s2 += red_s[1][w]; }
    const float mu   = s1 * (1.0f / H2);
    const float var  = s2 * (1.0f / H2) - mu * mu;
    const float rstd = rsqrtf(var + 1e-5f);

    // ---- LN + gate + v + nh (thread owns element tid) ----
    const float yz = (whz - mu)*rstd*rgz + rbz + wxz;
    const float yd = (whd - mu)*rstd*rgd + rbd + wxd;
    const float z  = 1.0f / (1.0f + __expf(-yz));
    vreg = vreg + z * (yd - vreg);
    const float nh = fmaxf(vreg, 0.0f);
    nh_s[cur][tid] = nh;
    if (ir == 0) hsbuf[(size_t)(t*BB + b)*HH + tid] = nh;
    if (t == TT - 1) return;           // uniform exit; decode kernel follows

    // prefetch next step's Wx (off critical path)
    wxz = Wx[(size_t)((t+1)*BB + b)*H2 + tid];
    wxd = Wx[(size_t)((t+1)*BB + b)*H2 + HH + tid];
    __syncthreads();                   // S1: nh_s[cur] ready

    // ---- phase B1: glo/gdv dots (capture nh frags) + modulator partials ----
    float glo = 0.0f, gdv = 0.0f;
    float4 h4q[4];
    {
      const float4* nh4 = reinterpret_cast<const float4*>(nh_s[cur]);
#pragma unroll
      for (int q = 0; q < 4; ++q) {
        h4q[q] = nh4[m + 32*q];
        glo += d4(wlo[q],  h4q[q]);
        gdv += d4(Wdvr[q], h4q[q]);
      }
#pragma unroll
      for (int off = 16; off >= 1; off >>= 1) {
        glo += __shfl_xor(glo, off);
        gdv += __shfl_xor(gdv, off);
      }
    }
    {
      const int r = tid >> 4, kk = tid & 15;
      float part = 0.0f;
#pragma unroll
      for (int j = 0; j < 32; ++j)
        part += hmw_s[r*HMW_P + kk + 16*j] * nh_s[cur][kk + 16*j];
#pragma unroll
      for (int off = 8; off >= 1; off >>= 1) part += __shfl_xor(part, off);
      if (kk == 0) mp_s[r] = fmaxf(part + hmb, 0.0f);
    }
    __syncthreads();                   // S2: mp_s ready

    // ---- rsm redundantly in every wave (no extra sync/broadcast) ----
    float r_b, s_b, c2t;
    {
      const float mp = mp_s[tid & 31];
      float a0 = mw0*mp, a1 = mw1*mp, a2 = mw2*mp;
#pragma unroll
      for (int off = 16; off >= 1; off >>= 1) {
        a0 += __shfl_xor(a0, off);
        a1 += __shfl_xor(a1, off);
        a2 += __shfl_xor(a2, off);
      }
      r_b = 1.0f / (1.0f + __expf(-(a0 + mb0)));
      s_b = 1.0f / (1.0f + __expf(-(a1 + mb1)));
      c2t = tau * (a2 + mb2);
    }

    // ---- te own-column update for next step (read [cur], write [1-cur]) ----
    {
      const float teo = te_s[cur][tid];
      te_s[1 - cur][tid] = teo + r_b * (nh_s[1 - cur][tid] - teo);
    }

    // ---- state update + plast; te_new recomputed in-register ----
    const float nh_i  = nh_s[cur][gi];
    const float teo_i = te_s[cur][gi];
    const float hp_i  = nh_s[1 - cur][gi];
    const float te_i  = teo_i + r_b * (hp_i - teo_i);
    float plast = 0.0f;
    {
      const float4* te4o = reinterpret_cast<const float4*>(te_s[cur]);
      const float4* hp4  = reinterpret_cast<const float4*>(nh_s[1 - cur]);
#pragma unroll
      for (int q = 0; q < 4; ++q) {
        const int J = m + 32*q;
        const float4 h4 = h4q[q];
        const float4 to = te4o[J];
        const float4 hp = hp4[J];
#define SGRU_UPD(C) { \
        float ten = to.C + r_b * (hp.C - to.C);             /* (1-r)te + r*h_prev */ \
        float o   = nh_i * ten - h4.C * te_i;               /* outer - outer^T    */ \
        float tEn = tEr[q].C + s_b * (o - tEr[q].C);        /* (1-s)tE + s*o      */ \
        tEr[q].C  = tEn;                                                             \
        float d   = c1t * dUr[q].C + c2t * tEn;             /* (1-tau)dU+tau*m*tE */ \
        d = fminf(d, upr[q].C); d = fmaxf(d, lor[q].C);     /* clip               */ \
        dUr[q].C  = d;                                                               \
        plast = fmaf(d, h4.C, plast); }
        SGRU_UPD(x) SGRU_UPD(y) SGRU_UPD(z) SGRU_UPD(w)
#undef SGRU_UPD
      }
#pragma unroll
      for (int off = 16; off >= 1; off >>= 1) plast += __shfl_xor(plast, off);
    }

    // ---- post Wh(t+1) with tag t+2 into parity 1-cur ----
    if (m == 0) {
      ull* ps = colvT + ((size_t)((1 - cur)*BB + b)*512 + gi)*2;
      const ull tg = (ull)(t + 2) << 32;
      st8(ps,     tg | (ull)__float_as_uint(glo + hbl));
      st8(ps + 1, tg | (ull)__float_as_uint(gdv + hbh + a_sp*plast));
    }
  }
}

// ---------------- tiled fp32 GEMM: C[M][N] = A[M][K=512] . W[N][K]^T + bias ----------------
#define GBM 64
#define GBN 32
#define GBK 32
__global__ __launch_bounds__(256) void gemm_tn(
    const float* __restrict__ A, const float* __restrict__ W,
    const float* __restrict__ bias, float* __restrict__ C,
    int M, int N)
{
  const int K = 512;
  const int nbn = N / GBN;
  const int m0 = (blockIdx.x / nbn) * GBM;
  const int n0 = (blockIdx.x % nbn) * GBN;
  const int tid = threadIdx.x;
  const int tx = tid & 15;   // n: tx*2
  const int ty = tid >> 4;   // m: ty*4
  const int lr = tid >> 3;   // 0..31 (load row)
  const int lc = tid & 7;    // 0..7  (k float4)
  __shared__ float As[GBK][68];
  __shared__ float Ws[GBK][36];
  float acc[4][2] = {};
  for (int kc = 0; kc < K; kc += GBK) {
    const float4 a0 = *reinterpret_cast<const float4*>(A + (size_t)(m0 + lr)*K      + kc + lc*4);
    const float4 a1 = *reinterpret_cast<const float4*>(A + (size_t)(m0 + lr + 32)*K + kc + lc*4);
    const float4 w0 = *reinterpret_cast<const float4*>(W + (size_t)(n0 + lr)*K      + kc + lc*4);
    __syncthreads();
    As[lc*4+0][lr] = a0.x; As[lc*4+1][lr] = a0.y; As[lc*4+2][lr] = a0.z; As[lc*4+3][lr] = a0.w;
    As[lc*4+0][lr+32] = a1.x; As[lc*4+1][lr+32] = a1.y; As[lc*4+2][lr+32] = a1.z; As[lc*4+3][lr+32] = a1.w;
    Ws[lc*4+0][lr] = w0.x; Ws[lc*4+1][lr] = w0.y; Ws[lc*4+2][lr] = w0.z; Ws[lc*4+3][lr] = w0.w;
    __syncthreads();
#pragma unroll
    for (int k = 0; k < GBK; ++k) {
      const float4 am = *reinterpret_cast<const float4*>(&As[k][ty*4]);
      const float2 wn = *reinterpret_cast<const float2*>(&Ws[k][tx*2]);
      acc[0][0] += am.x*wn.x; acc[0][1] += am.x*wn.y;
      acc[1][0] += am.y*wn.x; acc[1][1] += am.y*wn.y;
      acc[2][0] += am.z*wn.x; acc[2][1] += am.z*wn.y;
      acc[3][0] += am.w*wn.x; acc[3][1] += am.w*wn.y;
    }
  }
  const float bv0 = bias[n0 + tx*2], bv1 = bias[n0 + tx*2 + 1];
#pragma unroll
  for (int i = 0; i < 4; ++i) {
    C[(size_t)(m0 + ty*4 + i)*N + n0 + tx*2]     = acc[i][0] + bv0;
    C[(size_t)(m0 + ty*4 + i)*N + n0 + tx*2 + 1] = acc[i][1] + bv1;
  }
}

// ---------------- in-place row LayerNorm (256 rows) + zero the tagged exchange region ----------------
__global__ __launch_bounds__(256) void ln_apply(
    float* __restrict__ Wp, const float* __restrict__ g, const float* __restrict__ b,
    ull* __restrict__ colvT)
{
  const int row = blockIdx.x;
  const int tid = threadIdx.x;
  {  // zero 16384 tagged words across the 256 blocks (tag 0 = invalid)
    const int idx = row * 256 + tid;
    if (idx < 2*BB*512*2) colvT[idx] = 0ull;
  }
  float* rp = Wp + (size_t)row * H2;
  float4 v = *reinterpret_cast<const float4*>(rp + tid*4);
  float s1 = v.x + v.y + v.z + v.w;
  float s2 = v.x*v.x + v.y*v.y + v.z*v.z + v.w*v.w;
#pragma unroll
  for (int off = 32; off >= 1; off >>= 1) {
    s1 += __shfl_xor(s1, off);
    s2 += __shfl_xor(s2, off);
  }
  __shared__ float red[2][4];
  if ((tid & 63) == 0) { red[0][tid >> 6] = s1; red[1][tid >> 6] = s2; }
  __syncthreads();
  s1 = red[0][0] + red[0][1] + red[0][2] + red[0][3];
  s2 = red[1][0] + red[1][1] + red[1][2] + red[1][3];
  const float mu   = s1 * (1.0f / H2);
  const float var  = s2 * (1.0f / H2) - mu * mu;
  const float rstd = rsqrtf(var + 1e-5f);
  const float4 gv = *reinterpret_cast<const float4*>(g + tid*4);
  const float4 bv = *reinterpret_cast<const float4*>(b + tid*4);
  v.x = gv.x*(v.x - mu)*rstd + bv.x;
  v.y = gv.y*(v.y - mu)*rstd + bv.y;
  v.z = gv.z*(v.z - mu)*rstd + bv.z;
  v.w = gv.w*(v.w - mu)*rstd + bv.w;
  *reinterpret_cast<float4*>(rp + tid*4) = v;
}

extern "C" void kernel_launch(void* const* d_in, const int* in_sizes, int n_in,
                              void* d_out, int out_size, void* d_ws, size_t ws_size,
                              hipStream_t stream) {
  (void)in_sizes; (void)n_in; (void)out_size; (void)ws_size;
  const float* x        = (const float*)d_in[0];
  const float* h0       = (const float*)d_in[1];
  const float* v0       = (const float*)d_in[2];
  const float* dU0      = (const float*)d_in[3];
  const float* te0      = (const float*)d_in[4];   // trace_e0
  const float* tE0      = (const float*)d_in[5];   // trace_E0
  const float* x2h_w    = (const float*)d_in[6];
  const float* x2h_b    = (const float*)d_in[7];
  const float* h2h_w    = (const float*)d_in[8];
  const float* h2h_b    = (const float*)d_in[9];
  const float* lnx_g    = (const float*)d_in[10];
  const float* lnx_b    = (const float*)d_in[11];
  const float* lnh_g    = (const float*)d_in[12];
  const float* lnh_b    = (const float*)d_in[13];
  const float* h2mod_w  = (const float*)d_in[14];
  const float* h2mod_b  = (const float*)d_in[15];
  const float* mod2h_w  = (const float*)d_in[16];
  const float* mod2h_b  = (const float*)d_in[17];
  const float* alpha    = (const float*)d_in[18];
  const float* tau_U    = (const float*)d_in[19];
  const float* dec_w    = (const float*)d_in[20];
  const float* dec_b    = (const float*)d_in[21];

  float* ws = (float*)d_ws;

  // 1) Wx pre-LN GEMM: [256 x 1024] = x . x2h_w^T  (128 blocks)
  gemm_tn<<<(TT*BB/GBM) * (H2/GBN), 256, 0, stream>>>(x, x2h_w, x2h_b,
                                                      ws + OFF_WX, TT*BB, H2);
  // 2) LN in place (256 rows) + zero tagged exchange words
  ln_apply<<<TT*BB, 256, 0, stream>>>(ws + OFF_WX, lnx_g, lnx_b,
                                      (ull*)(ws + OFF_COLV));

  // 3) persistent recurrent kernel: 256 blocks (= #CUs), 512 threads
  sgru_persistent<<<256, 512, 0, stream>>>(h0, v0, dU0, tE0, te0,
                                           h2h_w, h2h_b, lnh_g, lnh_b,
                                           h2mod_w, h2mod_b, mod2h_w, mod2h_b,
                                           alpha, tau_U, ws);

  // 4) decode GEMM: out = hs . dec_w^T + dec_b  (64 blocks)
  gemm_tn<<<(TT*BB/GBM) * (OO/GBN), 256, 0, stream>>>(ws + OFF_HS, dec_w, dec_b,
                                                      (float*)d_out, TT*BB, OO);
}

// Round 5
// 194.510 us; speedup vs baseline: 1.3076x; 1.3076x over previous
//
#include <hip/hip_runtime.h>

// Problem dims
#define TT 32
#define BB 8
#define DD 512
#define HH 512
#define RR 32
#define OO 512
#define H2 1024

typedef unsigned int uint;
typedef uint u32x4 __attribute__((ext_vector_type(4)));

// d_ws float-index offsets (~1.70 MB used)
#define OFF_WX    0        // [TT*BB][H2]   262144  (pre-LN then LN'd in place)
#define OFF_HS    262144   // [TT*BB][HH]   131072
#define OFF_COLV  393216   // 8192 x u32x4 (16B records): [2][BB][512] = 131072 B

#define HMW_P 528   // 528 % 32 == 16 -> hmw LDS accesses are exact 2-way (free)

// ---- coherent (device-visible, L1/L2-bypass) coalesced 16B ops ----
__device__ __forceinline__ u32x4 ld16_coh(const u32x4* p) {
  u32x4 r;
  asm volatile("global_load_dwordx4 %0, %1, off sc0 sc1\n\ts_waitcnt vmcnt(0)"
               : "=v"(r) : "v"(p) : "memory");
  return r;
}
__device__ __forceinline__ void st16_coh(u32x4* p, u32x4 v) {
  asm volatile("global_store_dwordx4 %0, %1, off sc0 sc1"
               :: "v"(p), "v"(v) : "memory");
}
__device__ __forceinline__ float d4(const float4& a, const float4& b) {
  return a.x*b.x + a.y*b.y + a.z*b.z + a.w*b.w;
}

// ---------------- persistent recurrent kernel: tag-in-data sync, no barriers ----------------
__global__ __launch_bounds__(512, 1) void sgru_persistent(
    const float* __restrict__ h0,     const float* __restrict__ v0,
    const float* __restrict__ dU0,    const float* __restrict__ tE0,
    const float* __restrict__ te0,
    const float* __restrict__ h2h_w,  const float* __restrict__ h2h_b,
    const float* __restrict__ lnh_g,  const float* __restrict__ lnh_b,
    const float* __restrict__ h2mod_w,const float* __restrict__ h2mod_b,
    const float* __restrict__ mod2h_w,const float* __restrict__ mod2h_b,
    const float* __restrict__ alpha_p,const float* __restrict__ tau_p,
    float* __restrict__ ws)
{
  const int tid = threadIdx.x;
  const int b   = blockIdx.x & 7;    // consecutive blockIdx -> XCD round-robin
  const int ir  = blockIdx.x >> 3;   // row-group 0..31
  const int i0  = ir << 4;
  const int il  = tid >> 5;
  const int m   = tid & 31;
  const int gi  = i0 + il;

  const float* Wx = ws + OFF_WX;
  float* hsbuf    = ws + OFF_HS;
  u32x4* colvT    = (u32x4*)(ws + OFF_COLV);  // [parity][b][row] 16B records

  __shared__ float nh_s[2][HH];       // nh double buffer by parity
  __shared__ float te_s[2][HH];       // te double buffer by parity
  __shared__ float hmw_s[RR * HMW_P]; // staged h2mod_w
  __shared__ float mp_s[RR];
  __shared__ float red_s[2][8];

  const float a_sp  = log1pf(__expf(alpha_p[0]));
  const float inv_a = 1.0f / (a_sp + 1e-8f);
  const float tau   = 1.0f / (1.0f + __expf(-tau_p[0]));
  const float c1t   = 1.0f - tau;

  // ---- register-resident state: dU, tE, w_dv row, w_low row, clip bounds ----
  float4 dUr[4], tEr[4], Wdvr[4], wlo[4], upr[4], lor[4];
  {
    const size_t rowoff = ((size_t)b * HH + gi) * HH;
    const size_t whioff = (size_t)(HH + gi) * HH;
    const size_t wlooff = (size_t)gi * HH;
#pragma unroll
    for (int q = 0; q < 4; ++q) {
      const int J = m + 32*q;
      dUr[q] = *reinterpret_cast<const float4*>(dU0 + rowoff + 4*J);
      tEr[q] = *reinterpret_cast<const float4*>(tE0 + rowoff + 4*J);
      wlo[q] = *reinterpret_cast<const float4*>(h2h_w + wlooff + 4*J);
      const float4 w = *reinterpret_cast<const float4*>(h2h_w + whioff + 4*J);
      Wdvr[q] = w;
      float4 u, l;
      u.x =  fmaxf(1.0f - w.x, 0.0f) * inv_a;  l.x = -fmaxf(1.0f + w.x, 0.0f) * inv_a;
      u.y =  fmaxf(1.0f - w.y, 0.0f) * inv_a;  l.y = -fmaxf(1.0f + w.y, 0.0f) * inv_a;
      u.z =  fmaxf(1.0f - w.z, 0.0f) * inv_a;  l.z = -fmaxf(1.0f + w.z, 0.0f) * inv_a;
      u.w =  fmaxf(1.0f - w.w, 0.0f) * inv_a;  l.w = -fmaxf(1.0f + w.w, 0.0f) * inv_a;
      upr[q] = u; lor[q] = l;
    }
  }

  // ---- per-thread constants ----
  const float rgz = lnh_g[tid],      rbz = lnh_b[tid];
  const float rgd = lnh_g[HH + tid], rbd = lnh_b[HH + tid];
  const float hbl = h2h_b[gi], hbh = h2h_b[HH + gi];
  const float hmb = h2mod_b[tid >> 4];
  const float mw0 = mod2h_w[tid & 31];             // redundant per-wave rsm
  const float mw1 = mod2h_w[RR + (tid & 31)];
  const float mw2 = mod2h_w[2*RR + (tid & 31)];
  const float mb0 = mod2h_b[0], mb1 = mod2h_b[1], mb2 = mod2h_b[2];
  float vreg = v0[b*HH + tid];

  // ---- prologue: stage LDS ----
  nh_s[1][tid] = h0[b*HH + tid];     // "prev" for t=0
  te_s[0][tid] = te0[b*HH + tid];    // te entering step 0
  for (int idx = tid; idx < RR*HH; idx += 512)
    hmw_s[(idx >> 9)*HMW_P + (idx & 511)] = h2mod_w[idx];
  __syncthreads();

  // ---- prologue post: Wh(0) from h0/dU0, tag=1, parity 0 ----
  {
    const float4* h4p = reinterpret_cast<const float4*>(nh_s[1]);
    float glo = 0.0f, gdv = 0.0f, plast = 0.0f;
#pragma unroll
    for (int q = 0; q < 4; ++q) {
      const float4 h4 = h4p[m + 32*q];
      glo   += d4(wlo[q],  h4);
      gdv   += d4(Wdvr[q], h4);
      plast += d4(dUr[q],  h4);
    }
#pragma unroll
    for (int off = 16; off >= 1; off >>= 1) {
      glo   += __shfl_xor(glo, off);
      gdv   += __shfl_xor(gdv, off);
      plast += __shfl_xor(plast, off);
    }
    if (m == 0) {
      u32x4 rec;
      rec.x = __float_as_uint(glo + hbl);
      rec.y = 1u;
      rec.z = __float_as_uint(gdv + hbh + a_sp*plast);
      rec.w = 1u;
      st16_coh(colvT + (size_t)(0*BB + b)*512 + gi, rec);
    }
  }

  float wxz = Wx[(size_t)(0*BB + b)*H2 + tid];
  float wxd = Wx[(size_t)(0*BB + b)*H2 + HH + tid];

  for (int t = 0; t < TT; ++t) {
    const int cur = t & 1;
    const uint want = (uint)(t + 1);

    // ---- spin-gather: thread tid waits for row tid's 16B record (coalesced) ----
    const u32x4* p = colvT + (size_t)(cur*BB + b)*512 + tid;
    u32x4 r;
    for (;;) {
      r = ld16_coh(p);
      if (__all((r.y == want) & (r.w == want))) break;
      __builtin_amdgcn_s_sleep(2);
    }
    const float whz = __uint_as_float(r.x);
    const float whd = __uint_as_float(r.z);

    // ---- LN stats over 1024 (block-redundant, bitwise identical) ----
    float s1 = whz + whd, s2 = whz*whz + whd*whd;
#pragma unroll
    for (int off = 32; off >= 1; off >>= 1) {
      s1 += __shfl_xor(s1, off);
      s2 += __shfl_xor(s2, off);
    }
    if ((tid & 63) == 0) { red_s[0][tid >> 6] = s1; red_s[1][tid >> 6] = s2; }
    __syncthreads();                   // SYNC A
    s1 = 0.0f; s2 = 0.0f;
#pragma unroll
    for (int w = 0; w < 8; ++w) { s1 += red_s[0][w]; s2 += red_s[1][w]; }
    const float mu   = s1 * (1.0f / H2);
    const float var  = s2 * (1.0f / H2) - mu * mu;
    const float rstd = rsqrtf(var + 1e-5f);

    // ---- LN + gate + v + nh (thread owns element tid) ----
    const float yz = (whz - mu)*rstd*rgz + rbz + wxz;
    const float yd = (whd - mu)*rstd*rgd + rbd + wxd;
    const float z  = 1.0f / (1.0f + __expf(-yz));
    vreg = vreg + z * (yd - vreg);
    const float nh = fmaxf(vreg, 0.0f);
    nh_s[cur][tid] = nh;
    if (ir == 0) hsbuf[(size_t)(t*BB + b)*HH + tid] = nh;
    if (t == TT - 1) return;           // uniform exit; decode kernel follows

    // prefetch next step's Wx (off critical path)
    wxz = Wx[(size_t)((t+1)*BB + b)*H2 + tid];
    wxd = Wx[(size_t)((t+1)*BB + b)*H2 + HH + tid];
    __syncthreads();                   // SYNC S1: nh_s[cur] ready

    // ---- phase B1: glo/gdv dots (capture nh frags) + modulator partials ----
    float glo = 0.0f, gdv = 0.0f;
    float4 h4q[4];
    {
      const float4* nh4 = reinterpret_cast<const float4*>(nh_s[cur]);
#pragma unroll
      for (int q = 0; q < 4; ++q) {
        h4q[q] = nh4[m + 32*q];
        glo += d4(wlo[q],  h4q[q]);
        gdv += d4(Wdvr[q], h4q[q]);
      }
#pragma unroll
      for (int off = 16; off >= 1; off >>= 1) {
        glo += __shfl_xor(glo, off);
        gdv += __shfl_xor(gdv, off);
      }
    }
    {
      const int rr = tid >> 4, kk = tid & 15;
      float part = 0.0f;
#pragma unroll
      for (int j = 0; j < 32; ++j)
        part += hmw_s[rr*HMW_P + kk + 16*j] * nh_s[cur][kk + 16*j];
#pragma unroll
      for (int off = 8; off >= 1; off >>= 1) part += __shfl_xor(part, off);
      if (kk == 0) mp_s[rr] = fmaxf(part + hmb, 0.0f);
    }
    __syncthreads();                   // SYNC S2: mp_s ready

    // ---- rsm redundantly in every wave ----
    float r_b, s_b, c2t;
    {
      const float mp = mp_s[tid & 31];
      float a0 = mw0*mp, a1 = mw1*mp, a2 = mw2*mp;
#pragma unroll
      for (int off = 16; off >= 1; off >>= 1) {
        a0 += __shfl_xor(a0, off);
        a1 += __shfl_xor(a1, off);
        a2 += __shfl_xor(a2, off);
      }
      r_b = 1.0f / (1.0f + __expf(-(a0 + mb0)));
      s_b = 1.0f / (1.0f + __expf(-(a1 + mb1)));
      c2t = tau * (a2 + mb2);
    }

    // ---- te own-column update for next step (read [cur], write [1-cur]) ----
    {
      const float teo = te_s[cur][tid];
      te_s[1 - cur][tid] = teo + r_b * (nh_s[1 - cur][tid] - teo);
    }

    // ---- state update + plast; te_new recomputed in-register ----
    const float nh_i  = nh_s[cur][gi];
    const float teo_i = te_s[cur][gi];
    const float hp_i  = nh_s[1 - cur][gi];
    const float te_i  = teo_i + r_b * (hp_i - teo_i);
    float plast = 0.0f;
    {
      const float4* te4o = reinterpret_cast<const float4*>(te_s[cur]);
      const float4* hp4  = reinterpret_cast<const float4*>(nh_s[1 - cur]);
#pragma unroll
      for (int q = 0; q < 4; ++q) {
        const int J = m + 32*q;
        const float4 h4 = h4q[q];
        const float4 to = te4o[J];
        const float4 hp = hp4[J];
#define SGRU_UPD(C) { \
        float ten = to.C + r_b * (hp.C - to.C);             /* (1-r)te + r*h_prev */ \
        float o   = nh_i * ten - h4.C * te_i;               /* outer - outer^T    */ \
        float tEn = tEr[q].C + s_b * (o - tEr[q].C);        /* (1-s)tE + s*o      */ \
        tEr[q].C  = tEn;                                                             \
        float d   = c1t * dUr[q].C + c2t * tEn;             /* (1-tau)dU+tau*m*tE */ \
        d = fminf(d, upr[q].C); d = fmaxf(d, lor[q].C);     /* clip               */ \
        dUr[q].C  = d;                                                               \
        plast = fmaf(d, h4.C, plast); }
        SGRU_UPD(x) SGRU_UPD(y) SGRU_UPD(z) SGRU_UPD(w)
#undef SGRU_UPD
      }
#pragma unroll
      for (int off = 16; off >= 1; off >>= 1) plast += __shfl_xor(plast, off);
    }

    // ---- post Wh(t+1), tag t+2, parity 1-cur (16 contiguous 16B records) ----
    if (m == 0) {
      u32x4 rec;
      rec.x = __float_as_uint(glo + hbl);
      rec.y = (uint)(t + 2);
      rec.z = __float_as_uint(gdv + hbh + a_sp*plast);
      rec.w = (uint)(t + 2);
      st16_coh(colvT + (size_t)((1 - cur)*BB + b)*512 + gi, rec);
    }
  }
}

// ---------------- tiled fp32 GEMM: C[M][N] = A[M][K=512] . W[N][K]^T + bias ----------------
#define GBM 32
#define GBN 32
#define GBK 32
__global__ __launch_bounds__(256) void gemm_tn(
    const float* __restrict__ A, const float* __restrict__ W,
    const float* __restrict__ bias, float* __restrict__ C,
    int M, int N)
{
  const int K = 512;
  const int nbn = N / GBN;
  const int m0 = (blockIdx.x / nbn) * GBM;
  const int n0 = (blockIdx.x % nbn) * GBN;
  const int tid = threadIdx.x;
  const int tx = tid & 15;   // n: tx*2
  const int ty = tid >> 4;   // m: ty*2
  const int lr = tid >> 3;   // 0..31 (load row)
  const int lc = tid & 7;    // 0..7  (k float4)
  __shared__ float As[GBK][36];
  __shared__ float Ws[GBK][36];
  float acc[2][2] = {};
  for (int kc = 0; kc < K; kc += GBK) {
    const float4 a0 = *reinterpret_cast<const float4*>(A + (size_t)(m0 + lr)*K + kc + lc*4);
    const float4 w0 = *reinterpret_cast<const float4*>(W + (size_t)(n0 + lr)*K + kc + lc*4);
    __syncthreads();
    As[lc*4+0][lr] = a0.x; As[lc*4+1][lr] = a0.y; As[lc*4+2][lr] = a0.z; As[lc*4+3][lr] = a0.w;
    Ws[lc*4+0][lr] = w0.x; Ws[lc*4+1][lr] = w0.y; Ws[lc*4+2][lr] = w0.z; Ws[lc*4+3][lr] = w0.w;
    __syncthreads();
#pragma unroll
    for (int k = 0; k < GBK; ++k) {
      const float2 am = *reinterpret_cast<const float2*>(&As[k][ty*2]);
      const float2 wn = *reinterpret_cast<const float2*>(&Ws[k][tx*2]);
      acc[0][0] += am.x*wn.x; acc[0][1] += am.x*wn.y;
      acc[1][0] += am.y*wn.x; acc[1][1] += am.y*wn.y;
    }
  }
  const float b0 = bias[n0 + tx*2], b1 = bias[n0 + tx*2 + 1];
  C[(size_t)(m0 + ty*2 + 0)*N + n0 + tx*2]     = acc[0][0] + b0;
  C[(size_t)(m0 + ty*2 + 0)*N + n0 + tx*2 + 1] = acc[0][1] + b1;
  C[(size_t)(m0 + ty*2 + 1)*N + n0 + tx*2]     = acc[1][0] + b0;
  C[(size_t)(m0 + ty*2 + 1)*N + n0 + tx*2 + 1] = acc[1][1] + b1;
}

// ---------------- in-place row LayerNorm (256 rows) + zero the exchange region ----------------
__global__ __launch_bounds__(256) void ln_apply(
    float* __restrict__ Wp, const float* __restrict__ g, const float* __restrict__ b,
    u32x4* __restrict__ colvT)
{
  const int row = blockIdx.x;
  const int tid = threadIdx.x;
  {  // zero 8192 16B records (tag 0 = invalid) across first 32 blocks
    const int idx = row * 256 + tid;
    if (idx < 2*BB*512) {
      u32x4 z = {0u, 0u, 0u, 0u};
      colvT[idx] = z;
    }
  }
  float* rp = Wp + (size_t)row * H2;
  float4 v = *reinterpret_cast<const float4*>(rp + tid*4);
  float s1 = v.x + v.y + v.z + v.w;
  float s2 = v.x*v.x + v.y*v.y + v.z*v.z + v.w*v.w;
#pragma unroll
  for (int off = 32; off >= 1; off >>= 1) {
    s1 += __shfl_xor(s1, off);
    s2 += __shfl_xor(s2, off);
  }
  __shared__ float red[2][4];
  if ((tid & 63) == 0) { red[0][tid >> 6] = s1; red[1][tid >> 6] = s2; }
  __syncthreads();
  s1 = red[0][0] + red[0][1] + red[0][2] + red[0][3];
  s2 = red[1][0] + red[1][1] + red[1][2] + red[1][3];
  const float mu   = s1 * (1.0f / H2);
  const float var  = s2 * (1.0f / H2) - mu * mu;
  const float rstd = rsqrtf(var + 1e-5f);
  const float4 gv = *reinterpret_cast<const float4*>(g + tid*4);
  const float4 bv = *reinterpret_cast<const float4*>(b + tid*4);
  v.x = gv.x*(v.x - mu)*rstd + bv.x;
  v.y = gv.y*(v.y - mu)*rstd + bv.y;
  v.z = gv.z*(v.z - mu)*rstd + bv.z;
  v.w = gv.w*(v.w - mu)*rstd + bv.w;
  *reinterpret_cast<float4*>(rp + tid*4) = v;
}

extern "C" void kernel_launch(void* const* d_in, const int* in_sizes, int n_in,
                              void* d_out, int out_size, void* d_ws, size_t ws_size,
                              hipStream_t stream) {
  (void)in_sizes; (void)n_in; (void)out_size; (void)ws_size;
  const float* x        = (const float*)d_in[0];
  const float* h0       = (const float*)d_in[1];
  const float* v0       = (const float*)d_in[2];
  const float* dU0      = (const float*)d_in[3];
  const float* te0      = (const float*)d_in[4];   // trace_e0
  const float* tE0      = (const float*)d_in[5];   // trace_E0
  const float* x2h_w    = (const float*)d_in[6];
  const float* x2h_b    = (const float*)d_in[7];
  const float* h2h_w    = (const float*)d_in[8];
  const float* h2h_b    = (const float*)d_in[9];
  const float* lnx_g    = (const float*)d_in[10];
  const float* lnx_b    = (const float*)d_in[11];
  const float* lnh_g    = (const float*)d_in[12];
  const float* lnh_b    = (const float*)d_in[13];
  const float* h2mod_w  = (const float*)d_in[14];
  const float* h2mod_b  = (const float*)d_in[15];
  const float* mod2h_w  = (const float*)d_in[16];
  const float* mod2h_b  = (const float*)d_in[17];
  const float* alpha    = (const float*)d_in[18];
  const float* tau_U    = (const float*)d_in[19];
  const float* dec_w    = (const float*)d_in[20];
  const float* dec_b    = (const float*)d_in[21];

  float* ws = (float*)d_ws;

  // 1) Wx pre-LN GEMM: [256 x 1024] = x . x2h_w^T  (256 blocks)
  gemm_tn<<<(TT*BB/GBM) * (H2/GBN), 256, 0, stream>>>(x, x2h_w, x2h_b,
                                                      ws + OFF_WX, TT*BB, H2);
  // 2) LN in place (256 rows) + zero exchange records (tag 0 = invalid)
  ln_apply<<<TT*BB, 256, 0, stream>>>(ws + OFF_WX, lnx_g, lnx_b,
                                      (u32x4*)(ws + OFF_COLV));

  // 3) persistent recurrent kernel: 256 blocks (= #CUs), 512 threads
  sgru_persistent<<<256, 512, 0, stream>>>(h0, v0, dU0, tE0, te0,
                                           h2h_w, h2h_b, lnh_g, lnh_b,
                                           h2mod_w, h2mod_b, mod2h_w, mod2h_b,
                                           alpha, tau_U, ws);

  // 4) decode GEMM: out = hs . dec_w^T + dec_b  (128 blocks)
  gemm_tn<<<(TT*BB/GBM) * (OO/GBN), 256, 0, stream>>>(ws + OFF_HS, dec_w, dec_b,
                                                      (float*)d_out, TT*BB, OO);
}

// Round 6
// 191.095 us; speedup vs baseline: 1.3309x; 1.0179x over previous
//
#include <hip/hip_runtime.h>

// Problem dims
#define TT 32
#define BB 8
#define DD 512
#define HH 512
#define RR 32
#define OO 512
#define H2 1024

typedef unsigned int uint;
typedef float f32x2 __attribute__((ext_vector_type(2)));

// d_ws float-index offsets (~1.64 MB used)
#define OFF_WX    0        // [TT*BB][H2]   262144  (pre-LN then LN'd in place)
#define OFF_HS    262144   // [TT*BB][HH]   131072
#define OFF_COLV  393216   // [2][BB][512] f32x2 = 16384 floats
#define OFF_TAGS  409600   // [2][BB][32] u32 = 512 u32

#define HMW_P 528   // 528 % 32 == 16 -> hmw LDS accesses are exact 2-way (free)

// ---- coherent (device-visible, cache-bypass) coalesced ops ----
__device__ __forceinline__ uint ld4_coh(const uint* p) {
  uint r;
  asm volatile("global_load_dword %0, %1, off sc0 sc1\n\ts_waitcnt vmcnt(0)"
               : "=v"(r) : "v"(p) : "memory");
  return r;
}
__device__ __forceinline__ f32x2 ld8_coh(const f32x2* p) {
  f32x2 r;
  asm volatile("global_load_dwordx2 %0, %1, off sc0 sc1\n\ts_waitcnt vmcnt(0)"
               : "=v"(r) : "v"(p) : "memory");
  return r;
}
__device__ __forceinline__ void st8_coh(f32x2* p, f32x2 v) {
  asm volatile("global_store_dwordx2 %0, %1, off sc0 sc1" :: "v"(p), "v"(v) : "memory");
}
__device__ __forceinline__ void st4_coh(uint* p, uint v) {
  asm volatile("global_store_dword %0, %1, off sc0 sc1" :: "v"(p), "v"(v) : "memory");
}
__device__ __forceinline__ float d4(const float4& a, const float4& b) {
  return a.x*b.x + a.y*b.y + a.z*b.z + a.w*b.w;
}

// ---------------- persistent recurrent kernel: tiny-tag sync + bulk coalesced gather ----------------
__global__ __launch_bounds__(512, 1) void sgru_persistent(
    const float* __restrict__ h0,     const float* __restrict__ v0,
    const float* __restrict__ dU0,    const float* __restrict__ tE0,
    const float* __restrict__ te0,
    const float* __restrict__ h2h_w,  const float* __restrict__ h2h_b,
    const float* __restrict__ lnh_g,  const float* __restrict__ lnh_b,
    const float* __restrict__ h2mod_w,const float* __restrict__ h2mod_b,
    const float* __restrict__ mod2h_w,const float* __restrict__ mod2h_b,
    const float* __restrict__ alpha_p,const float* __restrict__ tau_p,
    float* __restrict__ ws)
{
  const int tid = threadIdx.x;
  const int b   = blockIdx.x & 7;    // consecutive blockIdx -> XCD round-robin
  const int ir  = blockIdx.x >> 3;   // row-group 0..31
  const int i0  = ir << 4;
  const int il  = tid >> 5;
  const int m   = tid & 31;
  const int gi  = i0 + il;

  const float* Wx = ws + OFF_WX;
  float* hsbuf    = ws + OFF_HS;
  f32x2* colvF    = (f32x2*)(ws + OFF_COLV);  // [parity][b][row] (Wh_z, Wh_dv)
  uint*  tagsP    = (uint*)(ws + OFF_TAGS);   // [parity][b][block]

  __shared__ float nh_s[2][HH];       // nh double buffer by parity
  __shared__ float te_s[2][HH];       // te double buffer by parity
  __shared__ float hmw_s[RR * HMW_P]; // staged h2mod_w
  __shared__ float mp_s[RR];
  __shared__ float red_s[2][8];

  const float a_sp  = log1pf(__expf(alpha_p[0]));
  const float inv_a = 1.0f / (a_sp + 1e-8f);
  const float tau   = 1.0f / (1.0f + __expf(-tau_p[0]));
  const float c1t   = 1.0f - tau;

  // ---- register-resident state: dU, tE, w_dv row, w_low row, clip bounds ----
  float4 dUr[4], tEr[4], Wdvr[4], wlo[4], upr[4], lor[4];
  {
    const size_t rowoff = ((size_t)b * HH + gi) * HH;
    const size_t whioff = (size_t)(HH + gi) * HH;
    const size_t wlooff = (size_t)gi * HH;
#pragma unroll
    for (int q = 0; q < 4; ++q) {
      const int J = m + 32*q;
      dUr[q] = *reinterpret_cast<const float4*>(dU0 + rowoff + 4*J);
      tEr[q] = *reinterpret_cast<const float4*>(tE0 + rowoff + 4*J);
      wlo[q] = *reinterpret_cast<const float4*>(h2h_w + wlooff + 4*J);
      const float4 w = *reinterpret_cast<const float4*>(h2h_w + whioff + 4*J);
      Wdvr[q] = w;
      float4 u, l;
      u.x =  fmaxf(1.0f - w.x, 0.0f) * inv_a;  l.x = -fmaxf(1.0f + w.x, 0.0f) * inv_a;
      u.y =  fmaxf(1.0f - w.y, 0.0f) * inv_a;  l.y = -fmaxf(1.0f + w.y, 0.0f) * inv_a;
      u.z =  fmaxf(1.0f - w.z, 0.0f) * inv_a;  l.z = -fmaxf(1.0f + w.z, 0.0f) * inv_a;
      u.w =  fmaxf(1.0f - w.w, 0.0f) * inv_a;  l.w = -fmaxf(1.0f + w.w, 0.0f) * inv_a;
      upr[q] = u; lor[q] = l;
    }
  }

  // ---- per-thread constants ----
  const float rgz = lnh_g[tid],      rbz = lnh_b[tid];
  const float rgd = lnh_g[HH + tid], rbd = lnh_b[HH + tid];
  const float hbl = h2h_b[gi], hbh = h2h_b[HH + gi];
  const float hmb = h2mod_b[tid >> 4];
  const float mw0 = mod2h_w[tid & 31];             // redundant per-wave rsm
  const float mw1 = mod2h_w[RR + (tid & 31)];
  const float mw2 = mod2h_w[2*RR + (tid & 31)];
  const float mb0 = mod2h_b[0], mb1 = mod2h_b[1], mb2 = mod2h_b[2];
  float vreg = v0[b*HH + tid];

  // ---- prologue: stage LDS ----
  nh_s[1][tid] = h0[b*HH + tid];     // "prev" for t=0
  te_s[0][tid] = te0[b*HH + tid];    // te entering step 0
  for (int idx = tid; idx < RR*HH; idx += 512)
    hmw_s[(idx >> 9)*HMW_P + (idx & 511)] = h2mod_w[idx];
  __syncthreads();

  // ---- prologue post: Wh(0) from h0/dU0 -> parity 0, then tag=1 ----
  {
    const float4* h4p = reinterpret_cast<const float4*>(nh_s[1]);
    float glo = 0.0f, gdv = 0.0f, plast = 0.0f;
#pragma unroll
    for (int q = 0; q < 4; ++q) {
      const float4 h4 = h4p[m + 32*q];
      glo   += d4(wlo[q],  h4);
      gdv   += d4(Wdvr[q], h4);
      plast += d4(dUr[q],  h4);
    }
#pragma unroll
    for (int off = 16; off >= 1; off >>= 1) {
      glo   += __shfl_xor(glo, off);
      gdv   += __shfl_xor(gdv, off);
      plast += __shfl_xor(plast, off);
    }
    if (m == 0) {
      f32x2 rec;
      rec.x = glo + hbl;
      rec.y = gdv + hbh + a_sp*plast;
      st8_coh(colvF + (size_t)(0*BB + b)*512 + gi, rec);
    }
    asm volatile("s_waitcnt vmcnt(0)" ::: "memory");
    __syncthreads();                 // all waves' record stores drained
    if (tid == 0) st4_coh(tagsP + (size_t)(0*BB + b)*32 + ir, 1u);
  }

  float wxz = Wx[(size_t)(0*BB + b)*H2 + tid];
  float wxd = Wx[(size_t)(0*BB + b)*H2 + HH + tid];

  for (int t = 0; t < TT; ++t) {
    const int cur = t & 1;
    const uint want = (uint)(t + 1);

    // ---- spin on the 32-tag line only (128 B; tiny coherent traffic) ----
    {
      const uint* tg = tagsP + (size_t)(cur*BB + b)*32;
      const int lane = tid & 63;
      for (;;) {
        uint v = want;
        if (lane < 32) v = ld4_coh(tg + lane);
        if (__all(v >= want)) break;
        __builtin_amdgcn_s_sleep(1);
      }
    }
    // ---- one-shot coalesced gather: thread tid reads its (z,dv) pair ----
    const f32x2 rec = ld8_coh(colvF + (size_t)(cur*BB + b)*512 + tid);
    const float whz = rec.x;
    const float whd = rec.y;

    // ---- LN stats over 1024 (block-redundant, bitwise identical) ----
    float s1 = whz + whd, s2 = whz*whz + whd*whd;
#pragma unroll
    for (int off = 32; off >= 1; off >>= 1) {
      s1 += __shfl_xor(s1, off);
      s2 += __shfl_xor(s2, off);
    }
    if ((tid & 63) == 0) { red_s[0][tid >> 6] = s1; red_s[1][tid >> 6] = s2; }
    __syncthreads();                   // SYNC A
    s1 = 0.0f; s2 = 0.0f;
#pragma unroll
    for (int w = 0; w < 8; ++w) { s1 += red_s[0][w]; s2 += red_s[1][w]; }
    const float mu   = s1 * (1.0f / H2);
    const float var  = s2 * (1.0f / H2) - mu * mu;
    const float rstd = rsqrtf(var + 1e-5f);

    // ---- LN + gate + v + nh (thread owns element tid) ----
    const float yz = (whz - mu)*rstd*rgz + rbz + wxz;
    const float yd = (whd - mu)*rstd*rgd + rbd + wxd;
    const float z  = 1.0f / (1.0f + __expf(-yz));
    vreg = vreg + z * (yd - vreg);
    const float nh = fmaxf(vreg, 0.0f);
    nh_s[cur][tid] = nh;
    if (ir == 0) hsbuf[(size_t)(t*BB + b)*HH + tid] = nh;
    if (t == TT - 1) return;           // uniform exit; decode kernel follows

    // prefetch next step's Wx (off critical path)
    wxz = Wx[(size_t)((t+1)*BB + b)*H2 + tid];
    wxd = Wx[(size_t)((t+1)*BB + b)*H2 + HH + tid];
    __syncthreads();                   // SYNC S1: nh_s[cur] ready

    // ---- phase B1: glo/gdv dots (capture nh frags) + modulator partials ----
    float glo = 0.0f, gdv = 0.0f;
    float4 h4q[4];
    {
      const float4* nh4 = reinterpret_cast<const float4*>(nh_s[cur]);
#pragma unroll
      for (int q = 0; q < 4; ++q) {
        h4q[q] = nh4[m + 32*q];
        glo += d4(wlo[q],  h4q[q]);
        gdv += d4(Wdvr[q], h4q[q]);
      }
#pragma unroll
      for (int off = 16; off >= 1; off >>= 1) {
        glo += __shfl_xor(glo, off);
        gdv += __shfl_xor(gdv, off);
      }
    }
    {
      const int rr = tid >> 4, kk = tid & 15;
      float part = 0.0f;
#pragma unroll
      for (int j = 0; j < 32; ++j)
        part += hmw_s[rr*HMW_P + kk + 16*j] * nh_s[cur][kk + 16*j];
#pragma unroll
      for (int off = 8; off >= 1; off >>= 1) part += __shfl_xor(part, off);
      if (kk == 0) mp_s[rr] = fmaxf(part + hmb, 0.0f);
    }
    __syncthreads();                   // SYNC S2: mp_s ready

    // ---- rsm redundantly in every wave ----
    float r_b, s_b, c2t;
    {
      const float mp = mp_s[tid & 31];
      float a0 = mw0*mp, a1 = mw1*mp, a2 = mw2*mp;
#pragma unroll
      for (int off = 16; off >= 1; off >>= 1) {
        a0 += __shfl_xor(a0, off);
        a1 += __shfl_xor(a1, off);
        a2 += __shfl_xor(a2, off);
      }
      r_b = 1.0f / (1.0f + __expf(-(a0 + mb0)));
      s_b = 1.0f / (1.0f + __expf(-(a1 + mb1)));
      c2t = tau * (a2 + mb2);
    }

    // ---- te own-column update for next step (read [cur], write [1-cur]) ----
    {
      const float teo = te_s[cur][tid];
      te_s[1 - cur][tid] = teo + r_b * (nh_s[1 - cur][tid] - teo);
    }

    // ---- state update + plast; te_new recomputed in-register ----
    const float nh_i  = nh_s[cur][gi];
    const float teo_i = te_s[cur][gi];
    const float hp_i  = nh_s[1 - cur][gi];
    const float te_i  = teo_i + r_b * (hp_i - teo_i);
    float plast = 0.0f;
    {
      const float4* te4o = reinterpret_cast<const float4*>(te_s[cur]);
      const float4* hp4  = reinterpret_cast<const float4*>(nh_s[1 - cur]);
#pragma unroll
      for (int q = 0; q < 4; ++q) {
        const int J = m + 32*q;
        const float4 h4 = h4q[q];
        const float4 to = te4o[J];
        const float4 hp = hp4[J];
#define SGRU_UPD(C) { \
        float ten = to.C + r_b * (hp.C - to.C);             /* (1-r)te + r*h_prev */ \
        float o   = nh_i * ten - h4.C * te_i;               /* outer - outer^T    */ \
        float tEn = tEr[q].C + s_b * (o - tEr[q].C);        /* (1-s)tE + s*o      */ \
        tEr[q].C  = tEn;                                                             \
        float d   = c1t * dUr[q].C + c2t * tEn;             /* (1-tau)dU+tau*m*tE */ \
        d = fminf(d, upr[q].C); d = fmaxf(d, lor[q].C);     /* clip               */ \
        dUr[q].C  = d;                                                               \
        plast = fmaf(d, h4.C, plast); }
        SGRU_UPD(x) SGRU_UPD(y) SGRU_UPD(z) SGRU_UPD(w)
#undef SGRU_UPD
      }
#pragma unroll
      for (int off = 16; off >= 1; off >>= 1) plast += __shfl_xor(plast, off);
    }

    // ---- post Wh(t+1) records, drain, then single per-block tag ----
    if (m == 0) {
      f32x2 rec2;
      rec2.x = glo + hbl;
      rec2.y = gdv + hbh + a_sp*plast;
      st8_coh(colvF + (size_t)((1 - cur)*BB + b)*512 + gi, rec2);
    }
    asm volatile("s_waitcnt vmcnt(0)" ::: "memory");
    __syncthreads();                 // all waves' record stores drained
    if (tid == 0) st4_coh(tagsP + (size_t)((1 - cur)*BB + b)*32 + ir, (uint)(t + 2));
  }
}

// ---------------- tiled fp32 GEMM: C[M][N] = A[M][K=512] . W[N][K]^T + bias ----------------
#define GBM 32
#define GBN 32
#define GBK 32
__global__ __launch_bounds__(256) void gemm_tn(
    const float* __restrict__ A, const float* __restrict__ W,
    const float* __restrict__ bias, float* __restrict__ C,
    int M, int N)
{
  const int K = 512;
  const int nbn = N / GBN;
  const int m0 = (blockIdx.x / nbn) * GBM;
  const int n0 = (blockIdx.x % nbn) * GBN;
  const int tid = threadIdx.x;
  const int tx = tid & 15;   // n: tx*2
  const int ty = tid >> 4;   // m: ty*2
  const int lr = tid >> 3;   // 0..31 (load row)
  const int lc = tid & 7;    // 0..7  (k float4)
  __shared__ float As[GBK][36];
  __shared__ float Ws[GBK][36];
  float acc[2][2] = {};
  for (int kc = 0; kc < K; kc += GBK) {
    const float4 a0 = *reinterpret_cast<const float4*>(A + (size_t)(m0 + lr)*K + kc + lc*4);
    const float4 w0 = *reinterpret_cast<const float4*>(W + (size_t)(n0 + lr)*K + kc + lc*4);
    __syncthreads();
    As[lc*4+0][lr] = a0.x; As[lc*4+1][lr] = a0.y; As[lc*4+2][lr] = a0.z; As[lc*4+3][lr] = a0.w;
    Ws[lc*4+0][lr] = w0.x; Ws[lc*4+1][lr] = w0.y; Ws[lc*4+2][lr] = w0.z; Ws[lc*4+3][lr] = w0.w;
    __syncthreads();
#pragma unroll
    for (int k = 0; k < GBK; ++k) {
      const float2 am = *reinterpret_cast<const float2*>(&As[k][ty*2]);
      const float2 wn = *reinterpret_cast<const float2*>(&Ws[k][tx*2]);
      acc[0][0] += am.x*wn.x; acc[0][1] += am.x*wn.y;
      acc[1][0] += am.y*wn.x; acc[1][1] += am.y*wn.y;
    }
  }
  const float b0 = bias[n0 + tx*2], b1 = bias[n0 + tx*2 + 1];
  C[(size_t)(m0 + ty*2 + 0)*N + n0 + tx*2]     = acc[0][0] + b0;
  C[(size_t)(m0 + ty*2 + 0)*N + n0 + tx*2 + 1] = acc[0][1] + b1;
  C[(size_t)(m0 + ty*2 + 1)*N + n0 + tx*2]     = acc[1][0] + b0;
  C[(size_t)(m0 + ty*2 + 1)*N + n0 + tx*2 + 1] = acc[1][1] + b1;
}

// ---------------- in-place row LayerNorm (256 rows) + zero tag words ----------------
__global__ __launch_bounds__(256) void ln_apply(
    float* __restrict__ Wp, const float* __restrict__ g, const float* __restrict__ b,
    uint* __restrict__ tags)
{
  const int row = blockIdx.x;
  const int tid = threadIdx.x;
  if (row == 0) {             // zero 512 tag words (tag 0 = invalid)
    tags[tid]       = 0u;
    tags[tid + 256] = 0u;
  }
  float* rp = Wp + (size_t)row * H2;
  float4 v = *reinterpret_cast<const float4*>(rp + tid*4);
  float s1 = v.x + v.y + v.z + v.w;
  float s2 = v.x*v.x + v.y*v.y + v.z*v.z + v.w*v.w;
#pragma unroll
  for (int off = 32; off >= 1; off >>= 1) {
    s1 += __shfl_xor(s1, off);
    s2 += __shfl_xor(s2, off);
  }
  __shared__ float red[2][4];
  if ((tid & 63) == 0) { red[0][tid >> 6] = s1; red[1][tid >> 6] = s2; }
  __syncthreads();
  s1 = red[0][0] + red[0][1] + red[0][2] + red[0][3];
  s2 = red[1][0] + red[1][1] + red[1][2] + red[1][3];
  const float mu   = s1 * (1.0f / H2);
  const float var  = s2 * (1.0f / H2) - mu * mu;
  const float rstd = rsqrtf(var + 1e-5f);
  const float4 gv = *reinterpret_cast<const float4*>(g + tid*4);
  const float4 bv = *reinterpret_cast<const float4*>(b + tid*4);
  v.x = gv.x*(v.x - mu)*rstd + bv.x;
  v.y = gv.y*(v.y - mu)*rstd + bv.y;
  v.z = gv.z*(v.z - mu)*rstd + bv.z;
  v.w = gv.w*(v.w - mu)*rstd + bv.w;
  *reinterpret_cast<float4*>(rp + tid*4) = v;
}

extern "C" void kernel_launch(void* const* d_in, const int* in_sizes, int n_in,
                              void* d_out, int out_size, void* d_ws, size_t ws_size,
                              hipStream_t stream) {
  (void)in_sizes; (void)n_in; (void)out_size; (void)ws_size;
  const float* x        = (const float*)d_in[0];
  const float* h0       = (const float*)d_in[1];
  const float* v0       = (const float*)d_in[2];
  const float* dU0      = (const float*)d_in[3];
  const float* te0      = (const float*)d_in[4];   // trace_e0
  const float* tE0      = (const float*)d_in[5];   // trace_E0
  const float* x2h_w    = (const float*)d_in[6];
  const float* x2h_b    = (const float*)d_in[7];
  const float* h2h_w    = (const float*)d_in[8];
  const float* h2h_b    = (const float*)d_in[9];
  const float* lnx_g    = (const float*)d_in[10];
  const float* lnx_b    = (const float*)d_in[11];
  const float* lnh_g    = (const float*)d_in[12];
  const float* lnh_b    = (const float*)d_in[13];
  const float* h2mod_w  = (const float*)d_in[14];
  const float* h2mod_b  = (const float*)d_in[15];
  const float* mod2h_w  = (const float*)d_in[16];
  const float* mod2h_b  = (const float*)d_in[17];
  const float* alpha    = (const float*)d_in[18];
  const float* tau_U    = (const float*)d_in[19];
  const float* dec_w    = (const float*)d_in[20];
  const float* dec_b    = (const float*)d_in[21];

  float* ws = (float*)d_ws;

  // 1) Wx pre-LN GEMM: [256 x 1024] = x . x2h_w^T  (256 blocks)
  gemm_tn<<<(TT*BB/GBM) * (H2/GBN), 256, 0, stream>>>(x, x2h_w, x2h_b,
                                                      ws + OFF_WX, TT*BB, H2);
  // 2) LN in place (256 rows) + zero tag words (tag 0 = invalid)
  ln_apply<<<TT*BB, 256, 0, stream>>>(ws + OFF_WX, lnx_g, lnx_b,
                                      (uint*)(ws + OFF_TAGS));

  // 3) persistent recurrent kernel: 256 blocks (= #CUs), 512 threads
  sgru_persistent<<<256, 512, 0, stream>>>(h0, v0, dU0, tE0, te0,
                                           h2h_w, h2h_b, lnh_g, lnh_b,
                                           h2mod_w, h2mod_b, mod2h_w, mod2h_b,
                                           alpha, tau_U, ws);

  // 4) decode GEMM: out = hs . dec_w^T + dec_b  (128 blocks)
  gemm_tn<<<(TT*BB/GBM) * (OO/GBN), 256, 0, stream>>>(ws + OFF_HS, dec_w, dec_b,
                                                      (float*)d_out, TT*BB, OO);
}